// Round 4
// baseline (500.338 us; speedup 1.0000x reference)
//
#include <hip/hip_runtime.h>

typedef __attribute__((ext_vector_type(8))) short short8;
typedef __attribute__((ext_vector_type(4))) float f32x4;

#define S_LEN 2048
#define DH 64

__device__ __forceinline__ unsigned short f2bf(float x) {
  unsigned u = __builtin_bit_cast(unsigned, x);
  u += 0x7fffu + ((u >> 16) & 1u);
  return (unsigned short)(u >> 16);
}

// ---- detect whether mask was passed as uint8 (stride 1) or int32 (stride 4)
__global__ void detect_stride_k(const unsigned char* __restrict__ m, int* flag) {
  __shared__ int any;
  if (threadIdx.x == 0) any = 0;
  __syncthreads();
  int acc = 0;
  for (int i = threadIdx.x; i < 4096; i += 256)
    if (i & 3) acc |= m[i];
  if (acc) atomicOr(&any, 1);
  __syncthreads();
  if (threadIdx.x == 0) *flag = any ? 1 : 4;
}

// ---- K: f32 -> bf16, row-major [bh][t][d]
__global__ void conv_k_kernel(const float* __restrict__ k, char* __restrict__ kbf) {
  int idx = blockIdx.x * 256 + threadIdx.x;  // 524288 threads, 8 elems each
  const float4* s = (const float4*)k + (size_t)idx * 2;
  float4 a = s[0], b = s[1];
  int4 o;
  o.x = (int)f2bf(a.x) | ((int)f2bf(a.y) << 16);
  o.y = (int)f2bf(a.z) | ((int)f2bf(a.w) << 16);
  o.z = (int)f2bf(b.x) | ((int)f2bf(b.y) << 16);
  o.w = (int)f2bf(b.z) | ((int)f2bf(b.w) << 16);
  ((int4*)kbf)[idx] = o;
}

// ---- V: f32 [bh][t][d] -> bf16 transposed [bh][d][t]
__global__ void trans_v_kernel(const float* __restrict__ v, char* __restrict__ vtbf) {
  int gt = blockIdx.x * 256 + threadIdx.x;
  int wid = gt >> 6;            // 16384 wave-jobs
  int lane = gt & 63;
  int bh = wid >> 9;
  int rem = wid & 511;
  int d0 = (rem >> 5) * 4;      // 0,4,...,60
  int t = (rem & 31) * 64 + lane;
  float4 val = *(const float4*)(v + ((size_t)bh * S_LEN + t) * DH + d0);
  unsigned short* o = (unsigned short*)vtbf;
  size_t base = ((size_t)bh * DH + d0) * S_LEN + t;
  o[base]             = f2bf(val.x);
  o[base + S_LEN]     = f2bf(val.y);
  o[base + 2 * S_LEN] = f2bf(val.z);
  o[base + 3 * S_LEN] = f2bf(val.w);
}

// ======= FUSED, barrier-free: each wave owns 32 q-rows end-to-end ==========
__global__ __launch_bounds__(256, 4)
void attn_fused(const float* __restrict__ qsrc,
                const unsigned char* __restrict__ maskb,
                const char* __restrict__ kbf,
                const char* __restrict__ vtbf,
                const int* __restrict__ flagp,
                float* __restrict__ out) {
  // per-wave P bounce chunk: [32 q rows][80 B] (stride 80 breaks bank aliasing)
  __shared__ __align__(16) char pbuf[4][2560];

  const int tid = threadIdx.x;
  const int lane = tid & 63;
  const int w = tid >> 6;
  const int l15 = lane & 15;
  const int g = lane >> 4;

  // XCD-aware swizzle: 512 blocks -> 4 consecutive bh per XCD
  int raw = blockIdx.x;
  int swz = (raw & 7) * 64 + (raw >> 3);
  const int bh = swz >> 4;
  const int rowblk = swz & 15;
  const int b = bh >> 4;
  const int q0 = rowblk * 128 + w * 32;   // this wave's 32 q-rows

  const int stride = *flagp;
  const unsigned char* mb = maskb + (size_t)b * S_LEN * S_LEN * (size_t)stride;

  // Q fragments: lane holds Q[q0+16qs+l15][32kc+8g+j]
  short8 qf[2][2];
#pragma unroll
  for (int qs = 0; qs < 2; ++qs)
#pragma unroll
    for (int kc = 0; kc < 2; ++kc) {
      const float* qp = qsrc + ((size_t)bh * S_LEN + q0 + 16 * qs + l15) * DH + 32 * kc + 8 * g;
      float4 x = *(const float4*)qp;
      float4 y = *(const float4*)(qp + 4);
      short8 f;
      f[0] = (short)f2bf(x.x); f[1] = (short)f2bf(x.y);
      f[2] = (short)f2bf(x.z); f[3] = (short)f2bf(x.w);
      f[4] = (short)f2bf(y.x); f[5] = (short)f2bf(y.y);
      f[6] = (short)f2bf(y.z); f[7] = (short)f2bf(y.w);
      qf[qs][kc] = f;
    }

  f32x4 acc[4][2];
#pragma unroll
  for (int i = 0; i < 4; ++i)
#pragma unroll
    for (int j = 0; j < 2; ++j)
      acc[i][j] = (f32x4){0.f, 0.f, 0.f, 0.f};
  float lp[2] = {0.f, 0.f};

  const char* kb = kbf + (size_t)bh * (S_LEN * DH * 2);
  const char* vb = vtbf + (size_t)bh * (DH * S_LEN * 2);
  char* pb = pbuf[w];

  // ---------------- PASS A: 32-t chunks, no barriers ----------------
  for (int t0 = 0; t0 < S_LEN; t0 += 32) {
    // K fragment loads (L2-resident): rows t0+l15, t0+16+l15
    const char* kr0 = kb + (size_t)(t0 + l15) * 128;
    const char* kr1 = kr0 + 16 * 128;
    short8 k00 = *(const short8*)(kr0 + 16 * g);
    short8 k01 = *(const short8*)(kr0 + 64 + 16 * g);
    short8 k10 = *(const short8*)(kr1 + 16 * g);
    short8 k11 = *(const short8*)(kr1 + 64 + 16 * g);
    // V^T fragment loads: rows d=16dr+l15, cols t0+8g..+8
    short8 av[4];
#pragma unroll
    for (int dr = 0; dr < 4; ++dr)
      av[dr] = *(const short8*)(vb + (size_t)(16 * dr + l15) * (S_LEN * 2) + t0 * 2 + 16 * g);

    // GEMM1 (swapped): sf[qs][tcr], lane holds S[q=q0+16qs+l15][t=t0+16tcr+4g+r]
    f32x4 sf[2][2];
    f32x4 z = (f32x4){0.f, 0.f, 0.f, 0.f};
#pragma unroll
    for (int qs = 0; qs < 2; ++qs) {
      f32x4 t00 = __builtin_amdgcn_mfma_f32_16x16x32_bf16(k00, qf[qs][0], z, 0, 0, 0);
      sf[qs][0] = __builtin_amdgcn_mfma_f32_16x16x32_bf16(k01, qf[qs][1], t00, 0, 0, 0);
      f32x4 t10 = __builtin_amdgcn_mfma_f32_16x16x32_bf16(k10, qf[qs][0], z, 0, 0, 0);
      sf[qs][1] = __builtin_amdgcn_mfma_f32_16x16x32_bf16(k11, qf[qs][1], t10, 0, 0, 0);
    }

    // mask + scale + exp-sum + pack into per-wave LDS chunk
#pragma unroll
    for (int qs = 0; qs < 2; ++qs) {
      const int q = q0 + 16 * qs + l15;
#pragma unroll
      for (int tcr = 0; tcr < 2; ++tcr) {
        const int t = t0 + 16 * tcr + 4 * g;
        size_t eidx = (size_t)q * S_LEN + t;
        int m0, m1, m2, m3;
        if (stride == 1) {
          unsigned mv = *(const unsigned*)(mb + eidx);
          m0 = mv & 0xff; m1 = (mv >> 8) & 0xff; m2 = (mv >> 16) & 0xff; m3 = (mv >> 24) & 0xff;
        } else {
          uint4 mv = *(const uint4*)(mb + eidx * 4);
          m0 = mv.x; m1 = mv.y; m2 = mv.z; m3 = mv.w;
        }
        float s0 = m0 ? -1e9f : sf[qs][tcr][0] * 0.125f;
        float s1 = m1 ? -1e9f : sf[qs][tcr][1] * 0.125f;
        float s2 = m2 ? -1e9f : sf[qs][tcr][2] * 0.125f;
        float s3 = m3 ? -1e9f : sf[qs][tcr][3] * 0.125f;
        lp[qs] += __expf(s0) + __expf(s1) + __expf(s2) + __expf(s3);
        int2 pk;
        pk.x = (int)f2bf(s0) | ((int)f2bf(s1) << 16);
        pk.y = (int)f2bf(s2) | ((int)f2bf(s3) << 16);
        *(int2*)(pb + (16 * qs + l15) * 80 + 32 * tcr + 8 * g) = pk;
      }
    }

    // P fragments back (wave-private LDS; HW lgkmcnt orders write->read)
    short8 p0 = *(const short8*)(pb + l15 * 80 + 16 * g);
    short8 p1 = *(const short8*)(pb + (16 + l15) * 80 + 16 * g);

    // GEMM2: acc^T[d][q] += V^T · P^T
#pragma unroll
    for (int dr = 0; dr < 4; ++dr) {
      acc[dr][0] = __builtin_amdgcn_mfma_f32_16x16x32_bf16(av[dr], p0, acc[dr][0], 0, 0, 0);
      acc[dr][1] = __builtin_amdgcn_mfma_f32_16x16x32_bf16(av[dr], p1, acc[dr][1], 0, 0, 0);
    }
  }

  // row sums (rows live on lanes {l15, +16, +32, +48})
  float inv[2];
#pragma unroll
  for (int qs = 0; qs < 2; ++qs) {
    float l = lp[qs];
    l += __shfl_xor(l, 16);
    l += __shfl_xor(l, 32);
    inv[qs] = 1.0f / l;
  }

  // write results: acc^T C-layout -> out[bh][q][d], float4 along d
#pragma unroll
  for (int dr = 0; dr < 4; ++dr)
#pragma unroll
    for (int qs = 0; qs < 2; ++qs) {
      const int q = q0 + 16 * qs + l15;
      float4 o;
      o.x = acc[dr][qs][0]; o.y = acc[dr][qs][1];
      o.z = acc[dr][qs][2]; o.w = acc[dr][qs][3];
      *(float4*)(out + ((size_t)bh * S_LEN + q) * DH + 16 * dr + 4 * g) = o;
    }

  // ---------------- PASS B: barrier-free attention stream ----------------
  float* att = out + (size_t)4194304 + (size_t)bh * S_LEN * S_LEN;
#pragma unroll 1
  for (int it = 0; it < 32; ++it) {
    const int tb = it * 64;
#pragma unroll
    for (int tc = 0; tc < 4; ++tc) {
      const char* rowp = kb + (size_t)(tb + 16 * tc + l15) * 128;
      short8 a0 = *(const short8*)(rowp + 16 * g);
      short8 a1 = *(const short8*)(rowp + 64 + 16 * g);
      const int t = tb + 16 * tc + 4 * g;
      f32x4 z = (f32x4){0.f, 0.f, 0.f, 0.f};
#pragma unroll
      for (int qs = 0; qs < 2; ++qs) {
        f32x4 t0f = __builtin_amdgcn_mfma_f32_16x16x32_bf16(a0, qf[qs][0], z, 0, 0, 0);
        f32x4 sff = __builtin_amdgcn_mfma_f32_16x16x32_bf16(a1, qf[qs][1], t0f, 0, 0, 0);
        const int q = q0 + 16 * qs + l15;
        const float iv = inv[qs];
        size_t eidx = (size_t)q * S_LEN + t;
        int m0, m1, m2, m3;
        if (stride == 1) {
          unsigned mv = *(const unsigned*)(mb + eidx);
          m0 = mv & 0xff; m1 = (mv >> 8) & 0xff; m2 = (mv >> 16) & 0xff; m3 = (mv >> 24) & 0xff;
        } else {
          uint4 mv = *(const uint4*)(mb + eidx * 4);
          m0 = mv.x; m1 = mv.y; m2 = mv.z; m3 = mv.w;
        }
        float s0 = m0 ? -1e9f : sff[0] * 0.125f;
        float s1 = m1 ? -1e9f : sff[1] * 0.125f;
        float s2 = m2 ? -1e9f : sff[2] * 0.125f;
        float s3 = m3 ? -1e9f : sff[3] * 0.125f;
        float4 e;
        e.x = __expf(s0) * iv;
        e.y = __expf(s1) * iv;
        e.z = __expf(s2) * iv;
        e.w = __expf(s3) * iv;
        *(float4*)(att + eidx) = e;
      }
    }
  }
}

extern "C" void kernel_launch(void* const* d_in, const int* in_sizes, int n_in,
                              void* d_out, int out_size, void* d_ws, size_t ws_size,
                              hipStream_t stream) {
  (void)in_sizes; (void)n_in; (void)out_size; (void)ws_size;
  const float* q = (const float*)d_in[0];
  const float* k = (const float*)d_in[1];
  const float* v = (const float*)d_in[2];
  const unsigned char* mask = (const unsigned char*)d_in[3];
  float* out = (float*)d_out;

  char* ws = (char*)d_ws;
  int* flag = (int*)ws;
  char* kbf = ws + 256;                           // 8 MiB bf16 K
  char* vtbf = ws + 256 + 8 * 1024 * 1024;        // 8 MiB bf16 V^T

  detect_stride_k<<<1, 256, 0, stream>>>(mask, flag);
  conv_k_kernel<<<2048, 256, 0, stream>>>(k, kbf);
  trans_v_kernel<<<4096, 256, 0, stream>>>(v, vtbf);
  attn_fused<<<512, 256, 0, stream>>>(q, mask, kbf, vtbf, flag, out);
}